// Round 11
// baseline (198.116 us; speedup 1.0000x reference)
//
#include <hip/hip_runtime.h>
#include <hip/hip_cooperative_groups.h>

namespace cg = cooperative_groups;

// FCOS Revision_PRED refinement — single cooperative dispatch with a
// checked launch + classic 3-dispatch fallback (round-10's coop launch
// failed silently: unchecked error, hardcoded GRID=1024 w/o capacity query).
//
// Outputs (flat float32, in return order):
//   [0, N2*4)              refined_boxes [N2,4]
//   [N2*4, N2*5)           s2            [N2]
//   [N2*5, N2*6)           c2            [N2] (int -> float)
//   [N2*6, N2*6+N1)        missing_mask  [N1] (bool -> 0/1)
//   [N2*6+N1, ...)         ious          [N1,N2]
//
// Algebraic reductions vs the reference:
//  - columns independent under suppression; <=8 suppressed + winner are the
//    column's entries >0.5 in (value desc, row asc) order -> top-9 suffices.
//  - entries >0.5 are rare: atomic append (e-major lists) not dense lists.
//  - missing_mask is suppression-invariant: row flags from v>=0.5 hits.
// Numerics:
//  - bulk v_rcp + 1 Newton (<=2ulp); values > 0.499999 recomputed __fdiv_rn
//    so everything near/above 0.5 is bit-exact vs numpy; __f*_rn blocks FMA
//    contraction in un.

constexpr int TOPK = 9;  // up to 8 suppressions + final winner

__device__ __forceinline__ void key_insert(unsigned long long (&t)[TOPK],
                                           unsigned long long pk) {
    if (pk > t[TOPK - 1]) {
#pragma unroll
        for (int j = TOPK - 1; j >= 0; --j) {
            const bool gt_cur  = pk > t[j];
            const bool gt_prev = (j > 0) ? (pk > t[j - 1]) : false;
            if (gt_cur) t[j] = gt_prev ? t[j - 1] : pk;
        }
    }
}

// ---- shared device bodies (used by both the fused and classic kernels) ----

__device__ __forceinline__ void iou_chunk_body(
    const float* __restrict__ b1, const float* __restrict__ b2,
    float* __restrict__ ious,
    unsigned int* __restrict__ cnt, unsigned long long* __restrict__ cand,
    unsigned char* __restrict__ rowflag,
    int n1, int n2, int c0, int r0, int r1, int cap)
{
    float4 bxv[4]; float ar[4];
#pragma unroll
    for (int k = 0; k < 4; ++k) {
        bxv[k] = reinterpret_cast<const float4*>(b2)[c0 + k];
        ar[k] = __fmul_rn(__fsub_rn(bxv[k].z, bxv[k].x),
                          __fsub_rn(bxv[k].w, bxv[k].y));
    }

    float* orow = ious + (size_t)r0 * n2 + c0;
    for (int r = r0; r < r1; ++r, orow += n2) {
        const float4 p = reinterpret_cast<const float4*>(b1)[r];  // uniform
        const float a1 = __fmul_rn(__fsub_rn(p.z, p.x), __fsub_rn(p.w, p.y));
        float v[4], ovs[4], uns[4];
#pragma unroll
        for (int k = 0; k < 4; ++k) {
            const float wx = fmaxf(__fsub_rn(fminf(p.z, bxv[k].z),
                                             fmaxf(p.x, bxv[k].x)), 0.0f);
            const float wy = fmaxf(__fsub_rn(fminf(p.w, bxv[k].w),
                                             fmaxf(p.y, bxv[k].y)), 0.0f);
            const float ov = __fmul_rn(wx, wy);
            const float un = fmaxf(__fsub_rn(__fadd_rn(a1, ar[k]), ov), 1e-6f);
            ovs[k] = ov; uns[k] = un;
            float rc = __builtin_amdgcn_rcpf(un);
            rc = rc * fmaf(-un, rc, 2.0f);        // 1 Newton step, <=2 ulp
            v[k] = ov * rc;
        }

        // near-threshold: exact recompute + side effects.
        // 0.499999 is ~17 ulps below 0.5 (covers the <=2ulp NR band).
        const float vmax = fmaxf(fmaxf(v[0], v[1]), fmaxf(v[2], v[3]));
        if (vmax > 0.499999f) {                    // rare wave branch
#pragma unroll
            for (int k = 0; k < 4; ++k) {
                if (v[k] > 0.499999f) {
                    const float ve = __fdiv_rn(ovs[k], uns[k]);
                    v[k] = ve;
                    if (ve >= 0.5f) {
                        rowflag[r] = 1;
                        if (ve > 0.5f) {
                            const unsigned int idx = atomicAdd(&cnt[c0 + k], 1u);
                            if (idx < (unsigned int)cap)
                                // (value desc, row asc) key: ties ->
                                // smaller r wins, as jnp.argmax.
                                cand[(size_t)idx * n2 + (c0 + k)] =
                                    ((unsigned long long)__float_as_uint(ve) << 32)
                                  | (unsigned long long)(~(unsigned int)r);
                        }
                    }
                }
            }
        }
        *reinterpret_cast<float4*>(orow) = make_float4(v[0], v[1], v[2], v[3]);
    }
}

__device__ __forceinline__ void refine_missing_body(
    const float* __restrict__ b1, const float* __restrict__ s1,
    const int* __restrict__ c1,
    const float* __restrict__ b2, const float* __restrict__ s2,
    const int* __restrict__ c2,
    const unsigned int* __restrict__ cnt,
    const unsigned long long* __restrict__ cand,
    const unsigned char* __restrict__ rowflag,
    float* __restrict__ out_boxes, float* __restrict__ out_s,
    float* __restrict__ out_c, float* __restrict__ out_m,
    float* __restrict__ ious,
    int n1, int n2, int cap, int tid)
{
    if (tid < n1)                                   // missing_mask part
        out_m[tid] = rowflag[tid] ? 0.0f : 1.0f;

    const int c = tid;
    if (c >= n2) return;

    unsigned long long t[TOPK];
#pragma unroll
    for (int j = 0; j < TOPK; ++j) t[j] = 0ull;     // 0 < any valid key

    const int n = (int)cnt[c];
    if (n <= cap) {
        const unsigned long long* L = cand + c;     // e-major: coalesced
        for (int e = 0; e < n; ++e)
            key_insert(t, L[(size_t)e * n2]);
    } else {                                        // overflow: rescan column
        for (int r = 0; r < n1; ++r) {
            const float v = ious[(size_t)r * n2 + c];
            if (v > 0.5f)
                key_insert(t, ((unsigned long long)__float_as_uint(v) << 32)
                            | (unsigned long long)(~(unsigned int)r));
        }
    }

    int m = 0;
#pragma unroll
    for (int j = 0; j < TOPK; ++j) m += (t[j] != 0ull) ? 1 : 0;

    int   ti[TOPK];
    float s1v[TOPK];
    const float s2c = s2[c];
#pragma unroll
    for (int j = 0; j < TOPK; ++j) {
        ti[j]  = (int)~(unsigned int)(t[j] & 0xffffffffull);
        s1v[j] = (j < m) ? s1[ti[j]] : 0.0f;
    }

    // k = length of maximal prefix with scores1 < scores2 (suppressed), cap 8
    int k = 0;
#pragma unroll
    for (int j = 0; j < 8; ++j)
        if (j < m && k == j && s1v[j] < s2c) k = j + 1;

    // scatter the suppressions (entries replaced by exactly 0.5)
#pragma unroll
    for (int j = 0; j < 8; ++j)
        if (j < k) ious[(size_t)ti[j] * n2 + c] = 0.5f;

    const bool refine = (k < m);
    int winner = 0; float wsc = 0.0f;
#pragma unroll
    for (int j = 0; j < TOPK; ++j)
        if (j == k) { winner = ti[j]; wsc = s1v[j]; }

    float4 ob; float os, oc;
    if (refine) {
        ob = reinterpret_cast<const float4*>(b1)[winner];
        os = wsc;
        oc = (float)c1[winner];
    } else {
        ob = reinterpret_cast<const float4*>(b2)[c];
        os = s2c;
        oc = (float)c2[c];
    }
    ob.x = fmaxf(ob.x, 0.0f); ob.y = fmaxf(ob.y, 0.0f);   // (b+|b|)*0.5
    ob.z = fmaxf(ob.z, 0.0f); ob.w = fmaxf(ob.w, 0.0f);
    reinterpret_cast<float4*>(out_boxes)[c] = ob;
    out_s[c] = os;
    out_c[c] = oc;
}

// ---------------------------------------------------------------------------
// Fused cooperative kernel: zero -> sync -> IoU -> sync -> refine+missing
// ---------------------------------------------------------------------------
__global__ __launch_bounds__(256, 4) void fcos_fused_kernel(
    const float* __restrict__ b1, const float* __restrict__ s1,
    const int* __restrict__ c1,
    const float* __restrict__ b2, const float* __restrict__ s2,
    const int* __restrict__ c2,
    float* __restrict__ out_boxes, float* __restrict__ out_s,
    float* __restrict__ out_c, float* __restrict__ out_m,
    float* __restrict__ ious,
    unsigned int* __restrict__ cnt, unsigned long long* __restrict__ cand,
    unsigned char* __restrict__ rowflag,
    int n1, int n2, int bx, int rps, int nchunk, int cap)
{
    cg::grid_group grid = cg::this_grid();
    const int tid = blockIdx.x * blockDim.x + threadIdx.x;
    const int nthreads = gridDim.x * blockDim.x;

    // ---- phase 0: zero cnt[n2] + rowflag[n1] (n1 % 4 == 0) ----------------
    {
        unsigned int* rf32 = reinterpret_cast<unsigned int*>(rowflag);
        const int zc = n2 + (n1 >> 2);
        for (int i = tid; i < zc; i += nthreads) {
            if (i < n2) cnt[i] = 0u;
            else        rf32[i - n2] = 0u;
        }
    }
    grid.sync();

    // ---- phase A ----------------------------------------------------------
    for (int chunk = blockIdx.x; chunk < nchunk; chunk += gridDim.x) {
        const int bxi = chunk % bx;
        const int sy  = chunk / bx;
        const int c0  = (bxi * (int)blockDim.x + (int)threadIdx.x) * 4;
        if (c0 >= n2) continue;
        const int r0 = sy * rps;
        const int r1 = min(r0 + rps, n1);
        iou_chunk_body(b1, b2, ious, cnt, cand, rowflag, n1, n2, c0, r0, r1, cap);
    }
    grid.sync();   // device-scope: cand/cnt/rowflag/ious visible

    // ---- phase B ----------------------------------------------------------
    refine_missing_body(b1, s1, c1, b2, s2, c2, cnt, cand, rowflag,
                        out_boxes, out_s, out_c, out_m, ious, n1, n2, cap, tid);
}

// ---------------------------------------------------------------------------
// Classic fallback kernels (round-5 proven path)
// ---------------------------------------------------------------------------
__global__ __launch_bounds__(256) void iou_cand_kernel(
    const float* __restrict__ b1, const float* __restrict__ b2,
    float* __restrict__ ious,
    unsigned int* __restrict__ cnt, unsigned long long* __restrict__ cand,
    unsigned char* __restrict__ rowflag,
    int n1, int n2, int rps, int cap)
{
    const int tid = blockIdx.x * blockDim.x + threadIdx.x;
    const int c0 = tid * 4;
    if (c0 >= n2) return;
    const int r0 = blockIdx.y * rps;
    const int r1 = min(r0 + rps, n1);
    iou_chunk_body(b1, b2, ious, cnt, cand, rowflag, n1, n2, c0, r0, r1, cap);
}

__global__ __launch_bounds__(64) void refine_missing_kernel(
    const float* __restrict__ b1, const float* __restrict__ s1,
    const int* __restrict__ c1,
    const float* __restrict__ b2, const float* __restrict__ s2,
    const int* __restrict__ c2,
    const unsigned int* __restrict__ cnt,
    const unsigned long long* __restrict__ cand,
    const unsigned char* __restrict__ rowflag,
    float* __restrict__ out_boxes, float* __restrict__ out_s,
    float* __restrict__ out_c, float* __restrict__ out_m,
    float* __restrict__ ious,
    int n1, int n2, int cap)
{
    const int tid = blockIdx.x * blockDim.x + threadIdx.x;
    refine_missing_body(b1, s1, c1, b2, s2, c2, cnt, cand, rowflag,
                        out_boxes, out_s, out_c, out_m, ious, n1, n2, cap, tid);
}

extern "C" void kernel_launch(void* const* d_in, const int* in_sizes, int n_in,
                              void* d_out, int out_size, void* d_ws, size_t ws_size,
                              hipStream_t stream) {
    (void)n_in; (void)out_size;
    const float* b1 = (const float*)d_in[0];
    const float* s1 = (const float*)d_in[1];
    const int*   c1 = (const int*)d_in[2];
    const float* b2 = (const float*)d_in[3];
    const float* s2 = (const float*)d_in[4];
    const int*   c2 = (const int*)d_in[5];
    int n1 = in_sizes[1];   // 8192
    int n2 = in_sizes[4];   // 4096

    float* out       = (float*)d_out;
    float* out_boxes = out;
    float* out_s     = out + (size_t)n2 * 4;
    float* out_c     = out_s + n2;
    float* out_m     = out_c + n2;
    float* out_ious  = out_m + n1;

    // ws: [cnt: n2 u32][rowflag: n1 u8][cand: cap*n2 u64, e-major]
    const size_t cnt_b    = (size_t)n2 * sizeof(unsigned int);
    const size_t flag_b   = (size_t)n1;
    const size_t cand_off = (cnt_b + flag_b + 15) & ~(size_t)15;
    int cap = 1024;                                // overflow path covers rest
    while (cap > 16 && cand_off + (size_t)cap * n2 * 8 > ws_size) cap >>= 1;
    unsigned int*       cnt     = (unsigned int*)d_ws;
    unsigned char*      rowflag = (unsigned char*)d_ws + cnt_b;
    unsigned long long* cand    = (unsigned long long*)((char*)d_ws + cand_off);

    int bx = (n2 / 4 + 255) / 256;                 // 4 at n2=4096
    int S = 2048 / bx; if (S < 1) S = 1; if (S > n1) S = n1;   // 512 splits
    int rps = (n1 + S - 1) / S;                    // 16 rows/chunk
    int nchunk = bx * S;                           // 2048 chunks

    // --- capacity-checked cooperative launch (host queries: capture-safe) ---
    hipError_t err = hipErrorUnknown;
    int bpc = 0, ncu = 0, dev = 0;
    (void)hipGetDevice(&dev);
    (void)hipDeviceGetAttribute(&ncu, hipDeviceAttributeMultiprocessorCount, dev);
    (void)hipOccupancyMaxActiveBlocksPerMultiprocessor(
        &bpc, (const void*)fcos_fused_kernel, 256, 0);
    int GRID = bpc * ncu;
    if (GRID > 1024)  GRID = 1024;
    if (GRID > nchunk) GRID = nchunk;
    if (GRID >= 32) {                              // phase B needs >= n1 threads
        void* args[] = {
            (void*)&b1, (void*)&s1, (void*)&c1, (void*)&b2, (void*)&s2,
            (void*)&c2, (void*)&out_boxes, (void*)&out_s, (void*)&out_c,
            (void*)&out_m, (void*)&out_ious, (void*)&cnt, (void*)&cand,
            (void*)&rowflag, (void*)&n1, (void*)&n2, (void*)&bx, (void*)&rps,
            (void*)&nchunk, (void*)&cap
        };
        err = hipLaunchCooperativeKernel((const void*)fcos_fused_kernel,
                                         dim3(GRID), dim3(256), args, 0, stream);
    }

    if (err != hipSuccess) {
        // --- classic 3-dispatch fallback (round-5 proven, ~51us) -----------
        (void)hipMemsetAsync(d_ws, 0, cnt_b + flag_b, stream);
        dim3 gridA(bx, S);
        iou_cand_kernel<<<gridA, 256, 0, stream>>>(b1, b2, out_ious, cnt, cand,
                                                   rowflag, n1, n2, rps, cap);
        const int ntot = max(n1, n2);
        refine_missing_kernel<<<(ntot + 63) / 64, 64, 0, stream>>>(
            b1, s1, c1, b2, s2, c2, cnt, cand, rowflag,
            out_boxes, out_s, out_c, out_m, out_ious, n1, n2, cap);
    }
}

// Round 12
// 46.212 us; speedup vs baseline: 4.2871x; 4.2871x over previous
//
#include <hip/hip_runtime.h>

// FCOS Revision_PRED refinement — round-5 proven 3-dispatch structure
// (memset 24KB -> IoU+candidates -> refine+missing) + ILP-batched candidate
// loads in B. Round-11 showed cooperative fusion costs ~100us/grid-sync on
// 8 XCDs (230us total at perfect traffic) -> dispatch boundaries are the
// cheap way to sequence phases on this chip.
//
// Measured facts driving this design:
//  - A pass (warm) = 134 MB / 16.8us = 8.0 TB/s store BW (round-9
//    differential) == spec write ceiling; A is bandwidth-optimal.
//  - candidates >0.5 are rare -> atomic append, e-major lists.
//  - missing_mask is suppression-invariant -> row flags from v>=0.5 hits.
// Numerics:
//  - bulk v_rcp + 1 Newton (<=2ulp); values > 0.499999 recomputed __fdiv_rn
//    so everything near/above 0.5 is bit-exact vs numpy; __f*_rn blocks FMA
//    contraction in un.
//
// Outputs (flat float32, in return order):
//   [0, N2*4)              refined_boxes [N2,4]
//   [N2*4, N2*5)           s2            [N2]
//   [N2*5, N2*6)           c2            [N2] (int -> float)
//   [N2*6, N2*6+N1)        missing_mask  [N1] (bool -> 0/1)
//   [N2*6+N1, ...)         ious          [N1,N2]

constexpr int TOPK = 9;  // up to 8 suppressions + final winner

__device__ __forceinline__ void key_insert(unsigned long long (&t)[TOPK],
                                           unsigned long long pk) {
    if (pk > t[TOPK - 1]) {
#pragma unroll
        for (int j = TOPK - 1; j >= 0; --j) {
            const bool gt_cur  = pk > t[j];
            const bool gt_prev = (j > 0) ? (pk > t[j - 1]) : false;
            if (gt_cur) t[j] = gt_prev ? t[j - 1] : pk;
        }
    }
}

// ---------------------------------------------------------------------------
// Kernel A: IoU matrix (4 cols/thread, float4 stores) + rare candidate
// append (e-major) + row flags. blockIdx.y = row split.
// ---------------------------------------------------------------------------
__global__ __launch_bounds__(256) void iou_cand_kernel(
    const float* __restrict__ b1, const float* __restrict__ b2,
    float* __restrict__ ious,
    unsigned int* __restrict__ cnt, unsigned long long* __restrict__ cand,
    unsigned char* __restrict__ rowflag,
    int n1, int n2, int rps, int cap)
{
    const int tid = blockIdx.x * blockDim.x + threadIdx.x;
    const int c0 = tid * 4;
    if (c0 >= n2) return;
    const int r0 = blockIdx.y * rps;
    const int r1 = min(r0 + rps, n1);

    float4 bxv[4]; float ar[4];
#pragma unroll
    for (int k = 0; k < 4; ++k) {
        bxv[k] = reinterpret_cast<const float4*>(b2)[c0 + k];
        ar[k] = __fmul_rn(__fsub_rn(bxv[k].z, bxv[k].x),
                          __fsub_rn(bxv[k].w, bxv[k].y));
    }

    float* orow = ious + (size_t)r0 * n2 + c0;
    for (int r = r0; r < r1; ++r, orow += n2) {
        const float4 p = reinterpret_cast<const float4*>(b1)[r];  // uniform
        const float a1 = __fmul_rn(__fsub_rn(p.z, p.x), __fsub_rn(p.w, p.y));
        float v[4], ovs[4], uns[4];
#pragma unroll
        for (int k = 0; k < 4; ++k) {
            const float wx = fmaxf(__fsub_rn(fminf(p.z, bxv[k].z),
                                             fmaxf(p.x, bxv[k].x)), 0.0f);
            const float wy = fmaxf(__fsub_rn(fminf(p.w, bxv[k].w),
                                             fmaxf(p.y, bxv[k].y)), 0.0f);
            const float ov = __fmul_rn(wx, wy);
            const float un = fmaxf(__fsub_rn(__fadd_rn(a1, ar[k]), ov), 1e-6f);
            ovs[k] = ov; uns[k] = un;
            float rc = __builtin_amdgcn_rcpf(un);
            rc = rc * fmaf(-un, rc, 2.0f);        // 1 Newton step, <=2 ulp
            v[k] = ov * rc;
        }

        // near-threshold: exact recompute + side effects.
        // 0.499999 is ~17 ulps below 0.5 (covers the <=2ulp NR band).
        const float vmax = fmaxf(fmaxf(v[0], v[1]), fmaxf(v[2], v[3]));
        if (vmax > 0.499999f) {                    // rare wave branch
#pragma unroll
            for (int k = 0; k < 4; ++k) {
                if (v[k] > 0.499999f) {
                    const float ve = __fdiv_rn(ovs[k], uns[k]);
                    v[k] = ve;
                    if (ve >= 0.5f) {
                        rowflag[r] = 1;
                        if (ve > 0.5f) {
                            const unsigned int idx = atomicAdd(&cnt[c0 + k], 1u);
                            if (idx < (unsigned int)cap)
                                // (value desc, row asc) key: ties ->
                                // smaller r wins, as jnp.argmax.
                                cand[(size_t)idx * n2 + (c0 + k)] =
                                    ((unsigned long long)__float_as_uint(ve) << 32)
                                  | (unsigned long long)(~(unsigned int)r);
                        }
                    }
                }
            }
        }
        *reinterpret_cast<float4*>(orow) = make_float4(v[0], v[1], v[2], v[3]);
    }
}

// ---------------------------------------------------------------------------
// Kernel B (fused refine + missing): per column, top-9 from the candidate
// list with 4-wide ILP-batched loads (top-9 of a multiset is insertion-
// order-invariant -> batching preserves semantics), simulate <=8
// suppressions, scatter the 0.5s, write boxes/scores/classes; threads in
// [0,n1) also write missing_mask. Overflow (cnt > cap): rescan column.
// ---------------------------------------------------------------------------
__global__ __launch_bounds__(64) void refine_missing_kernel(
    const float* __restrict__ b1, const float* __restrict__ s1,
    const int* __restrict__ c1,
    const float* __restrict__ b2, const float* __restrict__ s2,
    const int* __restrict__ c2,
    const unsigned int* __restrict__ cnt,
    const unsigned long long* __restrict__ cand,
    const unsigned char* __restrict__ rowflag,
    float* __restrict__ out_boxes, float* __restrict__ out_s,
    float* __restrict__ out_c, float* __restrict__ out_m,
    float* __restrict__ ious,
    int n1, int n2, int cap)
{
    const int tid = blockIdx.x * blockDim.x + threadIdx.x;

    if (tid < n1)                                   // missing_mask part
        out_m[tid] = rowflag[tid] ? 0.0f : 1.0f;

    const int c = tid;
    if (c >= n2) return;

    const float s2c = s2[c];                        // hoisted (overlaps cnt load)

    unsigned long long t[TOPK];
#pragma unroll
    for (int j = 0; j < TOPK; ++j) t[j] = 0ull;     // 0 < any valid key

    const int n = (int)cnt[c];
    if (n <= cap) {
        const unsigned long long* L = cand + c;     // e-major: coalesced
        int e = 0;
        for (; e + 4 <= n; e += 4) {                // 4 independent loads/iter
            const unsigned long long p0 = L[(size_t)(e + 0) * n2];
            const unsigned long long p1 = L[(size_t)(e + 1) * n2];
            const unsigned long long p2 = L[(size_t)(e + 2) * n2];
            const unsigned long long p3 = L[(size_t)(e + 3) * n2];
            key_insert(t, p0); key_insert(t, p1);
            key_insert(t, p2); key_insert(t, p3);
        }
        for (; e < n; ++e)
            key_insert(t, L[(size_t)e * n2]);
    } else {                                        // overflow: rescan column
        for (int r = 0; r < n1; ++r) {
            const float v = ious[(size_t)r * n2 + c];
            if (v > 0.5f)
                key_insert(t, ((unsigned long long)__float_as_uint(v) << 32)
                            | (unsigned long long)(~(unsigned int)r));
        }
    }

    int m = 0;
#pragma unroll
    for (int j = 0; j < TOPK; ++j) m += (t[j] != 0ull) ? 1 : 0;

    int   ti[TOPK];
    float s1v[TOPK];
#pragma unroll
    for (int j = 0; j < TOPK; ++j) {
        ti[j]  = (int)~(unsigned int)(t[j] & 0xffffffffull);
        s1v[j] = (j < m) ? s1[ti[j]] : 0.0f;        // independent gathers
    }

    // k = length of maximal prefix with scores1 < scores2 (suppressed), cap 8
    int k = 0;
#pragma unroll
    for (int j = 0; j < 8; ++j)
        if (j < m && k == j && s1v[j] < s2c) k = j + 1;

    // scatter the suppressions (entries replaced by exactly 0.5)
#pragma unroll
    for (int j = 0; j < 8; ++j)
        if (j < k) ious[(size_t)ti[j] * n2 + c] = 0.5f;

    const bool refine = (k < m);
    int winner = 0; float wsc = 0.0f;
#pragma unroll
    for (int j = 0; j < TOPK; ++j)
        if (j == k) { winner = ti[j]; wsc = s1v[j]; }

    float4 ob; float os, oc;
    if (refine) {
        ob = reinterpret_cast<const float4*>(b1)[winner];
        os = wsc;
        oc = (float)c1[winner];
    } else {
        ob = reinterpret_cast<const float4*>(b2)[c];
        os = s2c;
        oc = (float)c2[c];
    }
    ob.x = fmaxf(ob.x, 0.0f); ob.y = fmaxf(ob.y, 0.0f);   // (b+|b|)*0.5
    ob.z = fmaxf(ob.z, 0.0f); ob.w = fmaxf(ob.w, 0.0f);
    reinterpret_cast<float4*>(out_boxes)[c] = ob;
    out_s[c] = os;
    out_c[c] = oc;
}

extern "C" void kernel_launch(void* const* d_in, const int* in_sizes, int n_in,
                              void* d_out, int out_size, void* d_ws, size_t ws_size,
                              hipStream_t stream) {
    (void)n_in; (void)out_size;
    const float* b1 = (const float*)d_in[0];
    const float* s1 = (const float*)d_in[1];
    const int*   c1 = (const int*)d_in[2];
    const float* b2 = (const float*)d_in[3];
    const float* s2 = (const float*)d_in[4];
    const int*   c2 = (const int*)d_in[5];
    const int n1 = in_sizes[1];   // 8192
    const int n2 = in_sizes[4];   // 4096

    float* out       = (float*)d_out;
    float* out_boxes = out;
    float* out_s     = out + (size_t)n2 * 4;
    float* out_c     = out_s + n2;
    float* out_m     = out_c + n2;
    float* out_ious  = out_m + n1;

    // ws: [cnt: n2 u32][rowflag: n1 u8][cand: cap*n2 u64, e-major]
    const size_t cnt_b    = (size_t)n2 * sizeof(unsigned int);
    const size_t flag_b   = (size_t)n1;
    const size_t cand_off = (cnt_b + flag_b + 15) & ~(size_t)15;
    int cap = 1024;                                // overflow path covers rest
    while (cap > 16 && cand_off + (size_t)cap * n2 * 8 > ws_size) cap >>= 1;
    unsigned int*       cnt     = (unsigned int*)d_ws;
    unsigned char*      rowflag = (unsigned char*)d_ws + cnt_b;
    unsigned long long* cand    = (unsigned long long*)((char*)d_ws + cand_off);

    (void)hipMemsetAsync(d_ws, 0, cnt_b + flag_b, stream);

    const int bx = (n2 / 4 + 255) / 256;           // 4 at n2=4096
    int S = 2048 / bx; if (S < 1) S = 1; if (S > n1) S = n1;   // 512 splits
    const int rps = (n1 + S - 1) / S;              // 16 rows/block

    dim3 gridA(bx, S);
    iou_cand_kernel<<<gridA, 256, 0, stream>>>(b1, b2, out_ious, cnt, cand,
                                               rowflag, n1, n2, rps, cap);
    const int ntot = max(n1, n2);
    refine_missing_kernel<<<(ntot + 63) / 64, 64, 0, stream>>>(
        b1, s1, c1, b2, s2, c2, cnt, cand, rowflag,
        out_boxes, out_s, out_c, out_m, out_ious, n1, n2, cap);
}